// Round 1
// baseline (197.889 us; speedup 1.0000x reference)
//
#include <hip/hip_runtime.h>

// Multi-scale deformable attention forward.
//   value:              [16, 8400, 8, 32] fp32
//   spatial shapes      (80,80),(40,40),(20,20), offsets 0/6400/8000 (hardcoded)
//   sampling_locations: [16, 300, 8, 3, 4, 2] fp32
//   attention_weights:  [16, 300, 8, 3, 4] fp32
//   out:                [16, 300, 256] fp32
#define BS   16
#define LQ   300
#define NH   8
#define C    32
#define LV   8400
// bytes per position (nH*c*4B)
#define POS_BYTES 1024

__device__ __forceinline__ void sample_point(
    const char* __restrict__ vbase, float gx, float gy, float aw,
    int W, int H, int off, float4& acc)
{
    const float x = gx * (float)W - 0.5f;
    const float y = gy * (float)H - 0.5f;
    const float xf = floorf(x), yf = floorf(y);
    const int x0 = (int)xf, y0 = (int)yf;
    const int x1 = x0 + 1,  y1 = y0 + 1;
    const float lx = x - xf, ly = y - yf;
    const float hx = 1.f - lx, hy = 1.f - ly;

    float w00 = hx * hy * aw;
    float w10 = lx * hy * aw;
    float w01 = hx * ly * aw;
    float w11 = lx * ly * aw;

    const bool vx0 = (unsigned)x0 < (unsigned)W;
    const bool vx1 = (unsigned)x1 < (unsigned)W;
    const bool vy0 = (unsigned)y0 < (unsigned)H;
    const bool vy1 = (unsigned)y1 < (unsigned)H;
    w00 = (vx0 && vy0) ? w00 : 0.f;
    w10 = (vx1 && vy0) ? w10 : 0.f;
    w01 = (vx0 && vy1) ? w01 : 0.f;
    w11 = (vx1 && vy1) ? w11 : 0.f;

    const int xc0 = min(max(x0, 0), W - 1);
    const int xc1 = min(max(x1, 0), W - 1);
    const int yc0 = min(max(y0, 0), H - 1);
    const int yc1 = min(max(y1, 0), H - 1);

    // 32-bit byte offsets (max ~8.6 MB relative to vbase)
    const int r0 = off + yc0 * W;
    const int r1 = off + yc1 * W;
    const float4 v00 = *(const float4*)(vbase + ((r0 + xc0) << 10));
    const float4 v10 = *(const float4*)(vbase + ((r0 + xc1) << 10));
    const float4 v01 = *(const float4*)(vbase + ((r1 + xc0) << 10));
    const float4 v11 = *(const float4*)(vbase + ((r1 + xc1) << 10));

    acc.x += v00.x * w00 + v10.x * w10 + v01.x * w01 + v11.x * w11;
    acc.y += v00.y * w00 + v10.y * w10 + v01.y * w01 + v11.y * w11;
    acc.z += v00.z * w00 + v10.z * w10 + v01.z * w01 + v11.z * w11;
    acc.w += v00.w * w00 + v10.w * w10 + v01.w * w01 + v11.w * w11;
}

// One WAVE (64 lanes) per (b,q); each lane handles one (h, c-quad) and all
// 12 (level,point) samples. 256-thread blocks = 4 independent waves, no LDS,
// no __syncthreads, no reduction. Lane: c4 = lane&7, h = lane>>3.
// loc/attw for the lane's (b,q,h) loaded once as 9 float4's.
__global__ __launch_bounds__(256, 4) void msda_fwd(
    const float* __restrict__ value,
    const float* __restrict__ loc,
    const float* __restrict__ attw,
    float* __restrict__ out)
{
    const int t    = threadIdx.x;
    const int lane = t & 63;
    const int bq   = blockIdx.x * 4 + (t >> 6);   // wave index selects query
    const int c4   = lane & 7;
    const int h    = lane >> 3;
    const int b    = bq / LQ;

    // loc: (bq*NH+h)*24 floats (96 B, 16B-aligned). attw: *12 floats (48 B).
    const float4* lp4 = (const float4*)(loc  + (size_t)(bq * NH + h) * 24);
    const float4* ap4 = (const float4*)(attw + (size_t)(bq * NH + h) * 12);
    const char* vbase = (const char*)value
                      + (size_t)b * LV * POS_BYTES + h * (C * 4) + c4 * 16;

    // 12 sampling points: 6 float4 of (x,y) pairs + 3 float4 of weights.
    const float4 L0 = lp4[0], L1 = lp4[1], L2 = lp4[2];
    const float4 L3 = lp4[3], L4 = lp4[4], L5 = lp4[5];
    const float4 A0 = ap4[0], A1 = ap4[1], A2 = ap4[2];

    float4 acc = make_float4(0.f, 0.f, 0.f, 0.f);

    // level 0: 80x80, offset 0
    sample_point(vbase, L0.x, L0.y, A0.x, 80, 80, 0, acc);
    sample_point(vbase, L0.z, L0.w, A0.y, 80, 80, 0, acc);
    sample_point(vbase, L1.x, L1.y, A0.z, 80, 80, 0, acc);
    sample_point(vbase, L1.z, L1.w, A0.w, 80, 80, 0, acc);
    // level 1: 40x40, offset 6400
    sample_point(vbase, L2.x, L2.y, A1.x, 40, 40, 6400, acc);
    sample_point(vbase, L2.z, L2.w, A1.y, 40, 40, 6400, acc);
    sample_point(vbase, L3.x, L3.y, A1.z, 40, 40, 6400, acc);
    sample_point(vbase, L3.z, L3.w, A1.w, 40, 40, 6400, acc);
    // level 2: 20x20, offset 8000
    sample_point(vbase, L4.x, L4.y, A2.x, 20, 20, 8000, acc);
    sample_point(vbase, L4.z, L4.w, A2.y, 20, 20, 8000, acc);
    sample_point(vbase, L5.x, L5.y, A2.z, 20, 20, 8000, acc);
    sample_point(vbase, L5.z, L5.w, A2.w, 20, 20, 8000, acc);

    // out channel block (h*32 + c4*4 .. +3) -> float4 index h*8+c4 == lane.
    ((float4*)out)[(size_t)bq * 64 + lane] = acc;
}

extern "C" void kernel_launch(void* const* d_in, const int* in_sizes, int n_in,
                              void* d_out, int out_size, void* d_ws, size_t ws_size,
                              hipStream_t stream) {
    const float* value = (const float*)d_in[0];
    // d_in[1] = value_spatial_shapes: compile-time constant in reference
    const float* loc   = (const float*)d_in[2];
    const float* attw  = (const float*)d_in[3];
    float* out = (float*)d_out;

    const int grid = BS * LQ / 4;   // 1200 blocks, 4 waves = 4 queries each
    msda_fwd<<<grid, 256, 0, stream>>>(value, loc, attw, out);
}